// Round 11
// baseline (498.074 us; speedup 1.0000x reference)
//
#include <hip/hip_runtime.h>
#include <hip/hip_bf16.h>

#define HID 64

typedef float f32x4 __attribute__((ext_vector_type(4)));  // native vec for nontemporal builtins

// ---- bf16 helpers ----
__device__ __forceinline__ unsigned short f2bf(float f) {  // RNE f32->bf16
    unsigned u = __float_as_uint(f);
    return (unsigned short)((u + 0x7fffu + ((u >> 16) & 1u)) >> 16);
}
// a[0..7] += bf16x8 packed in uint4 (low ushort = even feat)
__device__ __forceinline__ void acc8(float* a, uint4 v) {
    a[0] += __uint_as_float(v.x << 16);
    a[1] += __uint_as_float(v.x & 0xffff0000u);
    a[2] += __uint_as_float(v.y << 16);
    a[3] += __uint_as_float(v.y & 0xffff0000u);
    a[4] += __uint_as_float(v.z << 16);
    a[5] += __uint_as_float(v.z & 0xffff0000u);
    a[6] += __uint_as_float(v.w << 16);
    a[7] += __uint_as_float(v.w & 0xffff0000u);
}

// ================= CSR build (by dst) =================

__global__ __launch_bounds__(256) void hist_part_kernel(
    const int* __restrict__ dst, int* __restrict__ cnt, int E, int psz) {
    int part = blockIdx.x & 7, chunk = blockIdx.x >> 3;
    int i = chunk * 256 + threadIdx.x;
    if (i >= E) return;
    int d = __builtin_nontemporal_load(&dst[i]);   // streaming: keep L2 for cnt
    if (d / psz == part) atomicAdd(&cnt[d], 1);
}

__global__ __launch_bounds__(256) void bsum_kernel(const int* __restrict__ cnt,
                                                   int* __restrict__ bsums, int N) {
    __shared__ int s[256];
    int tid = threadIdx.x, i = blockIdx.x * 256 + tid;
    s[tid] = (i < N) ? cnt[i] : 0;
    __syncthreads();
    for (int o = 128; o > 0; o >>= 1) {
        if (tid < o) s[tid] += s[tid + o];
        __syncthreads();
    }
    if (tid == 0) bsums[blockIdx.x] = s[0];
}

__global__ __launch_bounds__(512) void scan_bsums_kernel(int* __restrict__ bsums, int nblk) {
    __shared__ int s[512];
    int tid = threadIdx.x;
    int orig = (tid < nblk) ? bsums[tid] : 0;
    s[tid] = orig;
    __syncthreads();
    for (int off = 1; off < 512; off <<= 1) {
        int v = (tid >= off) ? s[tid - off] : 0;
        __syncthreads();
        s[tid] += v;
        __syncthreads();
    }
    if (tid < nblk) bsums[tid] = s[tid] - orig;
}

// nodeinfo[n] = {row_ptr, deg, bits(dinv), 0} -> single dependent load per row
__global__ __launch_bounds__(256) void rowptr_kernel(
    const int* __restrict__ cnt, const int* __restrict__ bsums,
    int4* __restrict__ nodeinfo, int* __restrict__ cursor, int N) {
    __shared__ int s[256];
    int tid = threadIdx.x, i = blockIdx.x * 256 + tid;
    int c = (i < N) ? cnt[i] : 0;
    s[tid] = c;
    __syncthreads();
    for (int off = 1; off < 256; off <<= 1) {
        int v = (tid >= off) ? s[tid - off] : 0;
        __syncthreads();
        s[tid] += v;
        __syncthreads();
    }
    if (i < N) {
        int excl = s[tid] - c + bsums[blockIdx.x];
        cursor[i] = excl;
        int4 ni;
        ni.x = excl;
        ni.y = c;
        ni.z = (int)__float_as_uint(rsqrtf((float)c + 1.0f));  // +1 self-loop
        ni.w = 0;
        nodeinfo[i] = ni;
    }
}

__global__ __launch_bounds__(256) void fill_part_kernel(
    const int* __restrict__ src, const int* __restrict__ dst,
    int* __restrict__ cursor, int* __restrict__ col, int E, int psz) {
    int part = blockIdx.x & 7, chunk = blockIdx.x >> 3;
    int i = chunk * 256 + threadIdx.x;
    if (i >= E) return;
    int d = __builtin_nontemporal_load(&dst[i]);
    if (d / psz == part) {
        int s = __builtin_nontemporal_load(&src[i]);
        int p = atomicAdd(&cursor[d], 1);
        __builtin_nontemporal_store(s, &col[p]);   // written once, read from L3 later
    }
}

// ================= shared gather core =================
// one wave per node; 8 lanes x uint4 per g row (128B); eighth = lane>>3 picks
// one of 8 edges per wave-load (1KB/load in flight, 2 loads unrolled).
// Result: every lane holds t[8] = aggregate (incl. self) for feats 8fo..8fo+7.
__device__ __forceinline__ void gather64(
    const uint4* __restrict__ g4, const int* __restrict__ col,
    int beg, int deg, int n, int N, int lane, float* t) {
    int eighth = lane >> 3, fo = lane & 7;
    float a0[8] = {}, a1[8] = {};
    for (int base = 0; base < deg; base += 64) {
        int rem = deg - base; rem = rem > 64 ? 64 : rem;
        int c = (lane < rem) ? __builtin_nontemporal_load(&col[beg + base + lane]) : N;
        int groups = (rem + 7) >> 3;
        int j = 0;
        for (; j + 2 <= groups; j += 2) {
            int s0 = __shfl(c, 8 * (j + 0) + eighth, 64);
            int s1 = __shfl(c, 8 * (j + 1) + eighth, 64);
            uint4 v0 = g4[(size_t)s0 * 8 + fo];   // cached: the reuse stream
            uint4 v1 = g4[(size_t)s1 * 8 + fo];
            acc8(a0, v0); acc8(a1, v1);
        }
        if (j < groups) {
            int s0 = __shfl(c, 8 * j + eighth, 64);
            uint4 v0 = g4[(size_t)s0 * 8 + fo];
            acc8(a0, v0);
        }
    }
    float sf[8] = {};
    acc8(sf, g4[(size_t)n * 8 + fo]);  // self-loop row
#pragma unroll
    for (int k = 0; k < 8; ++k) {
        float s = a0[k] + a1[k];
        s += __shfl_xor(s, 8, 64);
        s += __shfl_xor(s, 16, 64);
        s += __shfl_xor(s, 32, 64);
        t[k] = s + sf[k];
    }
}

// ================= conv1 GEMM: g = bf16((X@W)*dinv) =================
// register-resident W column per lane; X row broadcast via readlane. No LDS.

__global__ __launch_bounds__(256) void gemm_scale_kernel(
    const float* __restrict__ X, const float* __restrict__ W,
    const int4* __restrict__ nodeinfo, unsigned short* __restrict__ g, int N) {
    int tid = threadIdx.x, w = tid >> 6, lane = tid & 63;
    float Wreg[64];
#pragma unroll
    for (int k = 0; k < HID; ++k) Wreg[k] = W[k * HID + lane];
    int ngrp = (N + 4) / 4;  // covers sentinel row N
    for (int grp = blockIdx.x; grp < ngrp; grp += gridDim.x) {
        int row = grp * 4 + w;
        if (row > N) continue;
        if (row == N) { __builtin_nontemporal_store((unsigned short)0, &g[(size_t)N * HID + lane]); continue; }
        float xv = __builtin_nontemporal_load(&X[(size_t)row * HID + lane]);
        float dn = __uint_as_float(__builtin_amdgcn_readfirstlane((unsigned)nodeinfo[row].z));
        float acc = 0.f;
#pragma unroll
        for (int k = 0; k < HID; ++k) acc = fmaf(__shfl(xv, k, 64), Wreg[k], acc);
        __builtin_nontemporal_store(f2bf(acc * dn), &g[(size_t)row * HID + lane]);
    }
}

// ================= fused aggregate + epilogue + next-conv GEMM =================
// o_row = dinv*t + bias (+relu); g_out = bf16((o_row @ W) * dinv). No LDS:
// row broadcast via readlane of o[j] (identical across eighth-groups).

template <bool RELU>
__global__ __launch_bounds__(256) void agg_gemm_kernel(
    const unsigned short* __restrict__ g_in, const int4* __restrict__ nodeinfo,
    const int* __restrict__ col, const float* __restrict__ bias,
    const float* __restrict__ W, unsigned short* __restrict__ g_out, int N) {
    int tid = threadIdx.x, w = tid >> 6, lane = tid & 63;
    int fo = lane & 7;
    float Wreg[64];
#pragma unroll
    for (int k = 0; k < HID; ++k) Wreg[k] = W[k * HID + lane];
    float bb[8];
#pragma unroll
    for (int j = 0; j < 8; ++j) bb[j] = bias[8 * fo + j];
    const uint4* g4 = (const uint4*)g_in;
    int ngrp = (N + 4) / 4;
    for (int grp = blockIdx.x; grp < ngrp; grp += gridDim.x) {
        int n = grp * 4 + w;
        if (n > N) continue;
        if (n == N) { __builtin_nontemporal_store((unsigned short)0, &g_out[(size_t)N * HID + lane]); continue; }
        int4 ni = nodeinfo[n];
        int beg  = __builtin_amdgcn_readfirstlane(ni.x);
        int deg  = __builtin_amdgcn_readfirstlane(ni.y);
        float dn = __uint_as_float(__builtin_amdgcn_readfirstlane((unsigned)ni.z));
        float t[8];
        gather64(g4, col, beg, deg, n, N, lane, t);
        float o[8];
#pragma unroll
        for (int j = 0; j < 8; ++j) {
            o[j] = fmaf(dn, t[j], bb[j]);
            if (RELU) o[j] = fmaxf(o[j], 0.f);
        }
        float acc = 0.f;
#pragma unroll
        for (int q = 0; q < 8; ++q)
#pragma unroll
            for (int j = 0; j < 8; ++j)
                acc = fmaf(__shfl(o[j], q, 64), Wreg[8 * q + j], acc);
        __builtin_nontemporal_store(f2bf(acc * dn), &g_out[(size_t)n * HID + lane]);
    }
}

// ================= final aggregate + bias + log_softmax -> f32 out =================

__global__ __launch_bounds__(256) void agg_lsm_kernel(
    const unsigned short* __restrict__ g_in, const int4* __restrict__ nodeinfo,
    const int* __restrict__ col, const float* __restrict__ bias,
    float* __restrict__ out, int N) {
    int tid = threadIdx.x;
    int n = blockIdx.x * 4 + (tid >> 6);
    if (n >= N) return;
    int lane = tid & 63;
    int eighth = lane >> 3, fo = lane & 7;
    int4 ni = nodeinfo[n];
    int beg  = __builtin_amdgcn_readfirstlane(ni.x);
    int deg  = __builtin_amdgcn_readfirstlane(ni.y);
    float dn = __uint_as_float(__builtin_amdgcn_readfirstlane((unsigned)ni.z));
    const uint4* g4 = (const uint4*)g_in;
    float t[8];
    gather64(g4, col, beg, deg, n, N, lane, t);
    float v[8];
#pragma unroll
    for (int k = 0; k < 8; ++k) v[k] = fmaf(dn, t[k], bias[8 * fo + k]);
    float mx = v[0];
#pragma unroll
    for (int k = 1; k < 8; ++k) mx = fmaxf(mx, v[k]);
    mx = fmaxf(mx, __shfl_xor(mx, 1, 64));
    mx = fmaxf(mx, __shfl_xor(mx, 2, 64));
    mx = fmaxf(mx, __shfl_xor(mx, 4, 64));
    float sum = 0.f;
#pragma unroll
    for (int k = 0; k < 8; ++k) sum += expf(v[k] - mx);
    sum += __shfl_xor(sum, 1, 64);
    sum += __shfl_xor(sum, 2, 64);
    sum += __shfl_xor(sum, 4, 64);
    float ls = mx + logf(sum);
    if (eighth == 0) {
        f32x4 o0 = {v[0] - ls, v[1] - ls, v[2] - ls, v[3] - ls};
        f32x4 o1 = {v[4] - ls, v[5] - ls, v[6] - ls, v[7] - ls};
        f32x4* op = (f32x4*)out;
        __builtin_nontemporal_store(o0, &op[(size_t)n * 16 + 2 * fo]);
        __builtin_nontemporal_store(o1, &op[(size_t)n * 16 + 2 * fo + 1]);
    }
}

// ================= launcher =================

static inline size_t alignup(size_t x) { return (x + 255) & ~(size_t)255; }

extern "C" void kernel_launch(void* const* d_in, const int* in_sizes, int n_in,
                              void* d_out, int out_size, void* d_ws, size_t ws_size,
                              hipStream_t stream) {
    const float* x  = (const float*)d_in[0];
    const int*   ei = (const int*)d_in[1];
    const float* W1 = (const float*)d_in[2];
    const float* b1 = (const float*)d_in[3];
    const float* W2 = (const float*)d_in[4];
    const float* b2 = (const float*)d_in[5];

    const int N = in_sizes[0] / HID;  // 100000
    const int E = in_sizes[1] / 2;    // 1600000
    const int* src = ei;
    const int* dst = ei + E;

    const int nblk = (N + 255) / 256;  // 391 (<=512 required by scan)
    const int psz  = (N + 7) / 8;      // dst-range partition size

    char* w = (char*)d_ws;
    unsigned short* gA       = (unsigned short*)w; w += alignup((size_t)(N + 1) * HID * 2);
    unsigned short* gB       = (unsigned short*)w; w += alignup((size_t)(N + 1) * HID * 2);
    int4*           nodeinfo = (int4*)w;           w += alignup((size_t)N * 16);
    int*            cnt      = (int*)w;            w += alignup((size_t)N * 4);
    int*            cursor   = (int*)w;            w += alignup((size_t)N * 4);
    int*            col      = (int*)w;            w += alignup((size_t)E * 4);
    int*            bsums    = (int*)w;            w += alignup((size_t)nblk * 4);

    const int egrid  = (E + 255) / 256;
    const int ngrid  = (N + 3) / 4;  // final aggregate grid
    const int gsgrid = 2048;         // grid-stride kernels

    // ---- CSR build (once; reused by all 3 convs) ----
    (void)hipMemsetAsync(cnt, 0, (size_t)N * sizeof(int), stream);
    hist_part_kernel<<<egrid * 8, 256, 0, stream>>>(dst, cnt, E, psz);
    bsum_kernel<<<nblk, 256, 0, stream>>>(cnt, bsums, N);
    scan_bsums_kernel<<<1, 512, 0, stream>>>(bsums, nblk);
    rowptr_kernel<<<nblk, 256, 0, stream>>>(cnt, bsums, nodeinfo, cursor, N);
    fill_part_kernel<<<egrid * 8, 256, 0, stream>>>(src, dst, cursor, col, E, psz);

    // ---- conv1 GEMM: gA = (x@W1)*dinv ----
    gemm_scale_kernel<<<gsgrid, 256, 0, stream>>>(x, W1, nodeinfo, gA, N);
    // ---- conv1 agg + b1 | conv2 GEMM: gB = ((agg(gA)+b1)@W1)*dinv ----
    agg_gemm_kernel<false><<<gsgrid, 256, 0, stream>>>(gA, nodeinfo, col, b1, W1, gB, N);
    // ---- conv2 agg + b1 + relu | conv3 GEMM: gA = (relu(agg(gB)+b1)@W2)*dinv ----
    agg_gemm_kernel<true><<<gsgrid, 256, 0, stream>>>(gB, nodeinfo, col, b1, W2, gA, N);
    // ---- conv3 agg + b2 + log_softmax -> d_out ----
    agg_lsm_kernel<<<ngrid, 256, 0, stream>>>(gA, nodeinfo, col, b2, (float*)d_out, N);
}

// Round 13
// 424.842 us; speedup vs baseline: 1.1724x; 1.1724x over previous
//
#include <hip/hip_runtime.h>
#include <hip/hip_bf16.h>

#define HID 64

typedef float f32x4 __attribute__((ext_vector_type(4)));

// ---- bf16 helpers ----
__device__ __forceinline__ unsigned short f2bf(float f) {  // RNE f32->bf16
    unsigned u = __float_as_uint(f);
    return (unsigned short)((u + 0x7fffu + ((u >> 16) & 1u)) >> 16);
}
// a[0..7] += bf16x8 packed in uint4 (low ushort = even feat)
__device__ __forceinline__ void acc8(float* a, uint4 v) {
    a[0] += __uint_as_float(v.x << 16);
    a[1] += __uint_as_float(v.x & 0xffff0000u);
    a[2] += __uint_as_float(v.y << 16);
    a[3] += __uint_as_float(v.y & 0xffff0000u);
    a[4] += __uint_as_float(v.z << 16);
    a[5] += __uint_as_float(v.z & 0xffff0000u);
    a[6] += __uint_as_float(v.w << 16);
    a[7] += __uint_as_float(v.w & 0xffff0000u);
}

// ================= CSR build (by dst) =================

__global__ __launch_bounds__(256) void hist_part_kernel(
    const int* __restrict__ dst, int* __restrict__ cnt, int E, int psz) {
    int part = blockIdx.x & 7, chunk = blockIdx.x >> 3;
    int i = chunk * 256 + threadIdx.x;
    if (i >= E) return;
    int d = __builtin_nontemporal_load(&dst[i]);   // streaming read
    if (d / psz == part) atomicAdd(&cnt[d], 1);
}

__global__ __launch_bounds__(256) void bsum_kernel(const int* __restrict__ cnt,
                                                   int* __restrict__ bsums, int N) {
    __shared__ int s[256];
    int tid = threadIdx.x, i = blockIdx.x * 256 + tid;
    s[tid] = (i < N) ? cnt[i] : 0;
    __syncthreads();
    for (int o = 128; o > 0; o >>= 1) {
        if (tid < o) s[tid] += s[tid + o];
        __syncthreads();
    }
    if (tid == 0) bsums[blockIdx.x] = s[0];
}

__global__ __launch_bounds__(512) void scan_bsums_kernel(int* __restrict__ bsums, int nblk) {
    __shared__ int s[512];
    int tid = threadIdx.x;
    int orig = (tid < nblk) ? bsums[tid] : 0;
    s[tid] = orig;
    __syncthreads();
    for (int off = 1; off < 512; off <<= 1) {
        int v = (tid >= off) ? s[tid - off] : 0;
        __syncthreads();
        s[tid] += v;
        __syncthreads();
    }
    if (tid < nblk) bsums[tid] = s[tid] - orig;
}

// nodeinfo[n] = {row_ptr, deg, bits(dinv), 0}
__global__ __launch_bounds__(256) void rowptr_kernel(
    const int* __restrict__ cnt, const int* __restrict__ bsums,
    int4* __restrict__ nodeinfo, int* __restrict__ cursor, int N) {
    __shared__ int s[256];
    int tid = threadIdx.x, i = blockIdx.x * 256 + tid;
    int c = (i < N) ? cnt[i] : 0;
    s[tid] = c;
    __syncthreads();
    for (int off = 1; off < 256; off <<= 1) {
        int v = (tid >= off) ? s[tid - off] : 0;
        __syncthreads();
        s[tid] += v;
        __syncthreads();
    }
    if (i < N) {
        int excl = s[tid] - c + bsums[blockIdx.x];
        cursor[i] = excl;
        int4 ni;
        ni.x = excl;
        ni.y = c;
        ni.z = (int)__float_as_uint(rsqrtf((float)c + 1.0f));  // +1 self-loop
        ni.w = 0;
        nodeinfo[i] = ni;
    }
}

__global__ __launch_bounds__(256) void fill_part_kernel(
    const int* __restrict__ src, const int* __restrict__ dst,
    int* __restrict__ cursor, int* __restrict__ col, int E, int psz) {
    int part = blockIdx.x & 7, chunk = blockIdx.x >> 3;
    int i = chunk * 256 + threadIdx.x;
    if (i >= E) return;
    int d = __builtin_nontemporal_load(&dst[i]);
    if (d / psz == part) {
        int s = __builtin_nontemporal_load(&src[i]);
        int p = atomicAdd(&cursor[d], 1);
        col[p] = s;   // normal store: let the partitioned L2 window coalesce lines
    }
}

// ================= gather core (first col batch preloaded) =================
// one wave per node; 8 lanes x uint4 per g row (128B); eighth = lane>>3 picks
// one of 8 edges per wave-load. Every lane ends with t[8] = aggregate (incl.
// self) for feats 8fo..8fo+7.
__device__ __forceinline__ void gather64_pre(
    const uint4* __restrict__ g4, const int* __restrict__ col,
    int beg, int deg, int c, int n, int N, int lane, float* t) {
    int eighth = lane >> 3, fo = lane & 7;
    float a0[8] = {}, a1[8] = {};
    int base = 0;
    while (true) {
        int rem = deg - base; if (rem > 64) rem = 64;
        int groups = (rem + 7) >> 3;
        int j = 0;
        for (; j + 2 <= groups; j += 2) {
            int s0 = __shfl(c, 8 * (j + 0) + eighth, 64);
            int s1 = __shfl(c, 8 * (j + 1) + eighth, 64);
            uint4 v0 = g4[(size_t)s0 * 8 + fo];
            uint4 v1 = g4[(size_t)s1 * 8 + fo];
            acc8(a0, v0); acc8(a1, v1);
        }
        if (j < groups) {
            int s0 = __shfl(c, 8 * j + eighth, 64);
            uint4 v0 = g4[(size_t)s0 * 8 + fo];
            acc8(a0, v0);
        }
        base += 64;
        if (base >= deg) break;
        int r2 = deg - base;
        c = (lane < r2) ? __builtin_nontemporal_load(&col[beg + base + lane]) : N;
    }
    float sf[8] = {};
    acc8(sf, g4[(size_t)n * 8 + fo]);  // self-loop row
#pragma unroll
    for (int k = 0; k < 8; ++k) {
        float s = a0[k] + a1[k];
        s += __shfl_xor(s, 8, 64);
        s += __shfl_xor(s, 16, 64);
        s += __shfl_xor(s, 32, 64);
        t[k] = s + sf[k];
    }
}

// ================= conv1 GEMM: g = bf16((X@W)*dinv) =================
// grid-stride; W in LDS once per block; per-wave LDS x-slice (proven r9 form).

__global__ __launch_bounds__(256) void gemm_scale_kernel(
    const float* __restrict__ X, const float* __restrict__ W,
    const int4* __restrict__ nodeinfo, unsigned short* __restrict__ g, int N) {
    __shared__ float Ws[HID * HID];
    __shared__ float xs[4][HID];
    int tid = threadIdx.x;
    for (int i = tid; i < HID * HID; i += 256) Ws[i] = W[i];
    __syncthreads();
    int w = tid >> 6, c = tid & 63;
    float* xsw = xs[w];
    int ngrp = (N + 3) / 4;
    for (int grp = blockIdx.x; grp < ngrp; grp += gridDim.x) {
        int row = grp * 4 + w;
        if (row >= N) continue;
        xsw[c] = __builtin_nontemporal_load(&X[(size_t)row * HID + c]);
        float dn = __uint_as_float((unsigned)__builtin_amdgcn_readfirstlane(nodeinfo[row].z));
        float acc = 0.f;
#pragma unroll
        for (int k = 0; k < HID; ++k) acc = fmaf(xsw[k], Ws[k * HID + c], acc);
        __builtin_nontemporal_store(f2bf(acc * dn), &g[(size_t)row * HID + c]);
    }
}

// ================= fused aggregate + epilogue + next-conv GEMM =================
// Software-pipelined grid-stride: depth-2 nodeinfo prefetch, depth-1 col
// prefetch -> the ni->col->gather serial latency chain is hidden under the
// previous row's gather+GEMM. Scalars live in SGPRs via readfirstlane.

template <bool RELU>
__global__ __launch_bounds__(256) void agg_gemm_kernel(
    const unsigned short* __restrict__ g_in, const int4* __restrict__ nodeinfo,
    const int* __restrict__ col, const float* __restrict__ bias,
    const float* __restrict__ W, unsigned short* __restrict__ g_out, int N) {
    __shared__ float Ws[HID * HID];
    __shared__ float4 xs4[4][HID / 4];
    int tid = threadIdx.x;
    for (int i = tid; i < HID * HID; i += 256) Ws[i] = W[i];
    __syncthreads();
    int w = tid >> 6, lane = tid & 63;
    int eighth = lane >> 3, fo = lane & 7;
    const uint4* g4 = (const uint4*)g_in;
    float* xsw = (float*)xs4[w];
    float bb[8];
#pragma unroll
    for (int j = 0; j < 8; ++j) bb[j] = bias[8 * fo + j];
    const int gdim = gridDim.x;
    const int ngrp = (N + 3) / 4;
    int grp = blockIdx.x;
    if (grp >= ngrp) return;

    // prologue: cur row fully resolved; nxt nodeinfo in flight
    int n_cur = grp * 4 + w;
    bool v_cur = n_cur < N;
    int4 ni;
    ni.x = ni.y = ni.z = ni.w = 0;
    if (v_cur) ni = nodeinfo[n_cur];
    int beg_cur = __builtin_amdgcn_readfirstlane(ni.x);
    int deg_cur = __builtin_amdgcn_readfirstlane(ni.y);
    unsigned dnu_cur = (unsigned)__builtin_amdgcn_readfirstlane(ni.z);
    int c_cur = (v_cur && lane < deg_cur) ? __builtin_nontemporal_load(&col[beg_cur + lane]) : N;

    int grp_nxt = grp + gdim;
    int n_nxt = grp_nxt * 4 + w;
    bool v_nxt = (grp_nxt < ngrp) && (n_nxt < N);
    int4 ni_nxt;
    ni_nxt.x = ni_nxt.y = ni_nxt.z = ni_nxt.w = 0;
    if (v_nxt) ni_nxt = nodeinfo[n_nxt];

    while (true) {
        // stage A: resolve nxt meta (its load landed ~1 iteration ago);
        // issue nxt col load + n2 nodeinfo load.
        int beg_nxt = __builtin_amdgcn_readfirstlane(ni_nxt.x);
        int deg_nxt = __builtin_amdgcn_readfirstlane(ni_nxt.y);
        unsigned dnu_nxt = (unsigned)__builtin_amdgcn_readfirstlane(ni_nxt.z);
        int c_nxt = (v_nxt && lane < deg_nxt) ? __builtin_nontemporal_load(&col[beg_nxt + lane]) : N;
        int grp_n2 = grp_nxt + gdim;
        int n_n2 = grp_n2 * 4 + w;
        bool v_n2 = (grp_n2 < ngrp) && (n_n2 < N);
        int4 ni_n2;
        ni_n2.x = ni_n2.y = ni_n2.z = ni_n2.w = 0;
        if (v_n2) ni_n2 = nodeinfo[n_n2];

        // stage B: process cur row
        if (v_cur) {
            float dn = __uint_as_float(dnu_cur);
            float t[8];
            gather64_pre(g4, col, beg_cur, deg_cur, c_cur, n_cur, N, lane, t);
            float o[8];
#pragma unroll
            for (int j = 0; j < 8; ++j) {
                o[j] = fmaf(dn, t[j], bb[j]);
                if (RELU) o[j] = fmaxf(o[j], 0.f);
            }
            if (eighth == 0) {  // 8 lanes cover all fo -> full row to this wave's LDS slice
                xs4[w][2 * fo]     = make_float4(o[0], o[1], o[2], o[3]);
                xs4[w][2 * fo + 1] = make_float4(o[4], o[5], o[6], o[7]);
            }
            float acc = 0.f;   // same-wave DS ops are in order: write above, read below
#pragma unroll
            for (int k = 0; k < HID; ++k) acc = fmaf(xsw[k], Ws[k * HID + lane], acc);
            __builtin_nontemporal_store(f2bf(acc * dn), &g_out[(size_t)n_cur * HID + lane]);
        }
        if (grp_nxt >= ngrp) break;
        // shift pipeline
        n_cur = n_nxt; v_cur = v_nxt;
        beg_cur = beg_nxt; deg_cur = deg_nxt; dnu_cur = dnu_nxt; c_cur = c_nxt;
        grp_nxt = grp_n2; n_nxt = n_n2; v_nxt = v_n2; ni_nxt = ni_n2;
    }
}

// ================= final aggregate + bias + log_softmax -> f32 out =================
// same software pipeline, no GEMM.

__global__ __launch_bounds__(256) void agg_lsm_kernel(
    const unsigned short* __restrict__ g_in, const int4* __restrict__ nodeinfo,
    const int* __restrict__ col, const float* __restrict__ bias,
    float* __restrict__ out, int N) {
    int tid = threadIdx.x, w = tid >> 6, lane = tid & 63;
    int eighth = lane >> 3, fo = lane & 7;
    const uint4* g4 = (const uint4*)g_in;
    float bb[8];
#pragma unroll
    for (int j = 0; j < 8; ++j) bb[j] = bias[8 * fo + j];
    const int gdim = gridDim.x;
    const int ngrp = (N + 3) / 4;
    int grp = blockIdx.x;
    if (grp >= ngrp) return;

    int n_cur = grp * 4 + w;
    bool v_cur = n_cur < N;
    int4 ni;
    ni.x = ni.y = ni.z = ni.w = 0;
    if (v_cur) ni = nodeinfo[n_cur];
    int beg_cur = __builtin_amdgcn_readfirstlane(ni.x);
    int deg_cur = __builtin_amdgcn_readfirstlane(ni.y);
    unsigned dnu_cur = (unsigned)__builtin_amdgcn_readfirstlane(ni.z);
    int c_cur = (v_cur && lane < deg_cur) ? __builtin_nontemporal_load(&col[beg_cur + lane]) : N;

    int grp_nxt = grp + gdim;
    int n_nxt = grp_nxt * 4 + w;
    bool v_nxt = (grp_nxt < ngrp) && (n_nxt < N);
    int4 ni_nxt;
    ni_nxt.x = ni_nxt.y = ni_nxt.z = ni_nxt.w = 0;
    if (v_nxt) ni_nxt = nodeinfo[n_nxt];

    while (true) {
        int beg_nxt = __builtin_amdgcn_readfirstlane(ni_nxt.x);
        int deg_nxt = __builtin_amdgcn_readfirstlane(ni_nxt.y);
        unsigned dnu_nxt = (unsigned)__builtin_amdgcn_readfirstlane(ni_nxt.z);
        int c_nxt = (v_nxt && lane < deg_nxt) ? __builtin_nontemporal_load(&col[beg_nxt + lane]) : N;
        int grp_n2 = grp_nxt + gdim;
        int n_n2 = grp_n2 * 4 + w;
        bool v_n2 = (grp_n2 < ngrp) && (n_n2 < N);
        int4 ni_n2;
        ni_n2.x = ni_n2.y = ni_n2.z = ni_n2.w = 0;
        if (v_n2) ni_n2 = nodeinfo[n_n2];

        if (v_cur) {
            float dn = __uint_as_float(dnu_cur);
            float t[8];
            gather64_pre(g4, col, beg_cur, deg_cur, c_cur, n_cur, N, lane, t);
            float v[8];
#pragma unroll
            for (int k = 0; k < 8; ++k) v[k] = fmaf(dn, t[k], bb[k]);
            float mx = v[0];
#pragma unroll
            for (int k = 1; k < 8; ++k) mx = fmaxf(mx, v[k]);
            mx = fmaxf(mx, __shfl_xor(mx, 1, 64));
            mx = fmaxf(mx, __shfl_xor(mx, 2, 64));
            mx = fmaxf(mx, __shfl_xor(mx, 4, 64));
            float sum = 0.f;
#pragma unroll
            for (int k = 0; k < 8; ++k) sum += expf(v[k] - mx);
            sum += __shfl_xor(sum, 1, 64);
            sum += __shfl_xor(sum, 2, 64);
            sum += __shfl_xor(sum, 4, 64);
            float ls = mx + logf(sum);
            if (eighth == 0) {
                f32x4 o0 = {v[0] - ls, v[1] - ls, v[2] - ls, v[3] - ls};
                f32x4 o1 = {v[4] - ls, v[5] - ls, v[6] - ls, v[7] - ls};
                f32x4* op = (f32x4*)out;
                __builtin_nontemporal_store(o0, &op[(size_t)n_cur * 16 + 2 * fo]);
                __builtin_nontemporal_store(o1, &op[(size_t)n_cur * 16 + 2 * fo + 1]);
            }
        }
        if (grp_nxt >= ngrp) break;
        n_cur = n_nxt; v_cur = v_nxt;
        beg_cur = beg_nxt; deg_cur = deg_nxt; dnu_cur = dnu_nxt; c_cur = c_nxt;
        grp_nxt = grp_n2; n_nxt = n_n2; v_nxt = v_n2; ni_nxt = ni_n2;
    }
}

// ================= launcher =================

static inline size_t alignup(size_t x) { return (x + 255) & ~(size_t)255; }

extern "C" void kernel_launch(void* const* d_in, const int* in_sizes, int n_in,
                              void* d_out, int out_size, void* d_ws, size_t ws_size,
                              hipStream_t stream) {
    const float* x  = (const float*)d_in[0];
    const int*   ei = (const int*)d_in[1];
    const float* W1 = (const float*)d_in[2];
    const float* b1 = (const float*)d_in[3];
    const float* W2 = (const float*)d_in[4];
    const float* b2 = (const float*)d_in[5];

    const int N = in_sizes[0] / HID;  // 100000
    const int E = in_sizes[1] / 2;    // 1600000
    const int* src = ei;
    const int* dst = ei + E;

    const int nblk = (N + 255) / 256;  // 391 (<=512 required by scan)
    const int psz  = (N + 7) / 8;      // dst-range partition size

    char* w = (char*)d_ws;
    unsigned short* gA       = (unsigned short*)w; w += alignup((size_t)(N + 1) * HID * 2);
    unsigned short* gB       = (unsigned short*)w; w += alignup((size_t)(N + 1) * HID * 2);
    int4*           nodeinfo = (int4*)w;           w += alignup((size_t)N * 16);
    int*            cnt      = (int*)w;            w += alignup((size_t)N * 4);
    int*            cursor   = (int*)w;            w += alignup((size_t)N * 4);
    int*            col      = (int*)w;            w += alignup((size_t)E * 4);
    int*            bsums    = (int*)w;            w += alignup((size_t)nblk * 4);

    const int egrid  = (E + 255) / 256;
    const int gsgrid = 2048;  // grid-stride kernels

    // sentinel rows (index N) of both g buffers: zero once per launch
    (void)hipMemsetAsync(gA + (size_t)N * HID, 0, HID * sizeof(unsigned short), stream);
    (void)hipMemsetAsync(gB + (size_t)N * HID, 0, HID * sizeof(unsigned short), stream);

    // ---- CSR build (once; reused by all 3 convs) ----
    (void)hipMemsetAsync(cnt, 0, (size_t)N * sizeof(int), stream);
    hist_part_kernel<<<egrid * 8, 256, 0, stream>>>(dst, cnt, E, psz);
    bsum_kernel<<<nblk, 256, 0, stream>>>(cnt, bsums, N);
    scan_bsums_kernel<<<1, 512, 0, stream>>>(bsums, nblk);
    rowptr_kernel<<<nblk, 256, 0, stream>>>(cnt, bsums, nodeinfo, cursor, N);
    fill_part_kernel<<<egrid * 8, 256, 0, stream>>>(src, dst, cursor, col, E, psz);

    // ---- conv1 GEMM: gA = (x@W1)*dinv ----
    gemm_scale_kernel<<<gsgrid, 256, 0, stream>>>(x, W1, nodeinfo, gA, N);
    // ---- conv1 agg + b1 | conv2 GEMM: gB = ((agg(gA)+b1)@W1)*dinv ----
    agg_gemm_kernel<false><<<gsgrid, 256, 0, stream>>>(gA, nodeinfo, col, b1, W1, gB, N);
    // ---- conv2 agg + b1 + relu | conv3 GEMM: gA = (relu(agg(gB)+b1)@W2)*dinv ----
    agg_gemm_kernel<true><<<gsgrid, 256, 0, stream>>>(gB, nodeinfo, col, b1, W2, gA, N);
    // ---- conv3 agg + b2 + log_softmax -> d_out ----
    agg_lsm_kernel<<<gsgrid, 256, 0, stream>>>(gA, nodeinfo, col, b2, (float*)d_out, N);
}

// Round 14
// 415.420 us; speedup vs baseline: 1.1990x; 1.0227x over previous
//
#include <hip/hip_runtime.h>
#include <hip/hip_bf16.h>

#define HID 64

typedef float f32x4 __attribute__((ext_vector_type(4)));

// ---- bf16 helpers ----
__device__ __forceinline__ unsigned short f2bf(float f) {  // RNE f32->bf16
    unsigned u = __float_as_uint(f);
    return (unsigned short)((u + 0x7fffu + ((u >> 16) & 1u)) >> 16);
}
// a[0..7] += bf16x8 packed in uint4 (low ushort = even feat)
__device__ __forceinline__ void acc8(float* a, uint4 v) {
    a[0] += __uint_as_float(v.x << 16);
    a[1] += __uint_as_float(v.x & 0xffff0000u);
    a[2] += __uint_as_float(v.y << 16);
    a[3] += __uint_as_float(v.y & 0xffff0000u);
    a[4] += __uint_as_float(v.z << 16);
    a[5] += __uint_as_float(v.z & 0xffff0000u);
    a[6] += __uint_as_float(v.w << 16);
    a[7] += __uint_as_float(v.w & 0xffff0000u);
}

// ================= CSR build (by dst) =================

__global__ __launch_bounds__(256) void hist_part_kernel(
    const int* __restrict__ dst, int* __restrict__ cnt, int E, int psz) {
    int part = blockIdx.x & 7, chunk = blockIdx.x >> 3;
    int i = chunk * 256 + threadIdx.x;
    if (i >= E) return;
    int d = __builtin_nontemporal_load(&dst[i]);   // streaming read
    if (d / psz == part) atomicAdd(&cnt[d], 1);
}

__global__ __launch_bounds__(256) void bsum_kernel(const int* __restrict__ cnt,
                                                   int* __restrict__ bsums, int N) {
    __shared__ int s[256];
    int tid = threadIdx.x, i = blockIdx.x * 256 + tid;
    s[tid] = (i < N) ? cnt[i] : 0;
    __syncthreads();
    for (int o = 128; o > 0; o >>= 1) {
        if (tid < o) s[tid] += s[tid + o];
        __syncthreads();
    }
    if (tid == 0) bsums[blockIdx.x] = s[0];
}

__global__ __launch_bounds__(512) void scan_bsums_kernel(int* __restrict__ bsums, int nblk) {
    __shared__ int s[512];
    int tid = threadIdx.x;
    int orig = (tid < nblk) ? bsums[tid] : 0;
    s[tid] = orig;
    __syncthreads();
    for (int off = 1; off < 512; off <<= 1) {
        int v = (tid >= off) ? s[tid - off] : 0;
        __syncthreads();
        s[tid] += v;
        __syncthreads();
    }
    if (tid < nblk) bsums[tid] = s[tid] - orig;
}

// nodeinfo[n] = {row_ptr, deg, bits(dinv), 0}
__global__ __launch_bounds__(256) void rowptr_kernel(
    const int* __restrict__ cnt, const int* __restrict__ bsums,
    int4* __restrict__ nodeinfo, int* __restrict__ cursor, int N) {
    __shared__ int s[256];
    int tid = threadIdx.x, i = blockIdx.x * 256 + tid;
    int c = (i < N) ? cnt[i] : 0;
    s[tid] = c;
    __syncthreads();
    for (int off = 1; off < 256; off <<= 1) {
        int v = (tid >= off) ? s[tid - off] : 0;
        __syncthreads();
        s[tid] += v;
        __syncthreads();
    }
    if (i < N) {
        int excl = s[tid] - c + bsums[blockIdx.x];
        cursor[i] = excl;
        int4 ni;
        ni.x = excl;
        ni.y = c;
        ni.z = (int)__float_as_uint(rsqrtf((float)c + 1.0f));  // +1 self-loop
        ni.w = 0;
        nodeinfo[i] = ni;
    }
}

__global__ __launch_bounds__(256) void fill_part_kernel(
    const int* __restrict__ src, const int* __restrict__ dst,
    int* __restrict__ cursor, int* __restrict__ col, int E, int psz) {
    int part = blockIdx.x & 7, chunk = blockIdx.x >> 3;
    int i = chunk * 256 + threadIdx.x;
    if (i >= E) return;
    int d = __builtin_nontemporal_load(&dst[i]);
    if (d / psz == part) {
        int s = __builtin_nontemporal_load(&src[i]);
        int p = atomicAdd(&cursor[d], 1);
        col[p] = s;   // normal store: partitioned L2 window coalesces lines
    }
}

// ================= gather core (first col batch preloaded; r9-proven) ======
__device__ __forceinline__ void gather64_pre(
    const uint4* __restrict__ g4, const int* __restrict__ col,
    int beg, int deg, int c, int n, int N, int lane, float* t) {
    int eighth = lane >> 3, fo = lane & 7;
    float a0[8] = {}, a1[8] = {};
    int base = 0;
    while (true) {
        int rem = deg - base; if (rem > 64) rem = 64;
        int groups = (rem + 7) >> 3;
        int j = 0;
        for (; j + 2 <= groups; j += 2) {
            int s0 = __shfl(c, 8 * (j + 0) + eighth, 64);
            int s1 = __shfl(c, 8 * (j + 1) + eighth, 64);
            uint4 v0 = g4[(size_t)s0 * 8 + fo];
            uint4 v1 = g4[(size_t)s1 * 8 + fo];
            acc8(a0, v0); acc8(a1, v1);
        }
        if (j < groups) {
            int s0 = __shfl(c, 8 * j + eighth, 64);
            uint4 v0 = g4[(size_t)s0 * 8 + fo];
            acc8(a0, v0);
        }
        base += 64;
        if (base >= deg) break;
        int r2 = deg - base;
        c = (lane < r2) ? __builtin_nontemporal_load(&col[beg + base + lane]) : N;
    }
    float sf[8] = {};
    acc8(sf, g4[(size_t)n * 8 + fo]);  // self-loop row
#pragma unroll
    for (int k = 0; k < 8; ++k) {
        float s = a0[k] + a1[k];
        s += __shfl_xor(s, 8, 64);
        s += __shfl_xor(s, 16, 64);
        s += __shfl_xor(s, 32, 64);
        t[k] = s + sf[k];
    }
}

// ================= conv1 GEMM: g = bf16((X@W)*dinv) (r13, unchanged) =======

__global__ __launch_bounds__(256) void gemm_scale_kernel(
    const float* __restrict__ X, const float* __restrict__ W,
    const int4* __restrict__ nodeinfo, unsigned short* __restrict__ g, int N) {
    __shared__ float Ws[HID * HID];
    __shared__ float xs[4][HID];
    int tid = threadIdx.x;
    for (int i = tid; i < HID * HID; i += 256) Ws[i] = W[i];
    __syncthreads();
    int w = tid >> 6, c = tid & 63;
    float* xsw = xs[w];
    int ngrp = (N + 3) / 4;
    for (int grp = blockIdx.x; grp < ngrp; grp += gridDim.x) {
        int row = grp * 4 + w;
        if (row >= N) continue;
        xsw[c] = __builtin_nontemporal_load(&X[(size_t)row * HID + c]);
        float dn = __uint_as_float((unsigned)__builtin_amdgcn_readfirstlane(nodeinfo[row].z));
        float acc = 0.f;
#pragma unroll
        for (int k = 0; k < HID; ++k) acc = fmaf(xsw[k], Ws[k * HID + c], acc);
        __builtin_nontemporal_store(f2bf(acc * dn), &g[(size_t)row * HID + c]);
    }
}

// ================= fused aggregate + epilogue + next-conv GEMM =============
// REGISTER GEMM (no LDS): lane l (s=l&7, q=l>>3) holds the 8x8 W block
// W[8s+j][8q+i] as 32 packed-bf16 regs. After the gather reduce, lane l's
// t[j] = feat 8s+j, so partials p[i] = sum_j o[j]*W[8s+j][8q+i] need no data
// movement. A 3-round butterfly over s (xor 1/2/4, keeping index bits matching
// s) reduces across slices and lands full col l on lane l. DS ops/row drop
// ~164 -> ~40 (the measured DS-issue bottleneck of r9/r13).

template <bool RELU>
__global__ __launch_bounds__(256, 4) void agg_gemm_kernel(
    const unsigned short* __restrict__ g_in, const int4* __restrict__ nodeinfo,
    const int* __restrict__ col, const float* __restrict__ bias,
    const float* __restrict__ W, unsigned short* __restrict__ g_out, int N) {
    int tid = threadIdx.x, w = tid >> 6, lane = tid & 63;
    int s = lane & 7, q = lane >> 3;
    // W block -> registers (bf16 pair packed along i; low16 = even i)
    unsigned Wp[32];
#pragma unroll
    for (int j = 0; j < 8; ++j)
#pragma unroll
        for (int i2 = 0; i2 < 4; ++i2) {
            float w0 = W[(8 * s + j) * HID + 8 * q + 2 * i2];
            float w1 = W[(8 * s + j) * HID + 8 * q + 2 * i2 + 1];
            Wp[j * 4 + i2] = (unsigned)f2bf(w0) | ((unsigned)f2bf(w1) << 16);
        }
    float bb[8];
#pragma unroll
    for (int j = 0; j < 8; ++j) bb[j] = bias[8 * s + j];
    const uint4* g4 = (const uint4*)g_in;
    const int ngrp = (N + 3) / 4;
    for (int grp = blockIdx.x; grp < ngrp; grp += gridDim.x) {
        int n = grp * 4 + w;
        if (n >= N) continue;
        int4 ni = nodeinfo[n];
        int beg = __builtin_amdgcn_readfirstlane(ni.x);
        int deg = __builtin_amdgcn_readfirstlane(ni.y);
        float dn = __uint_as_float((unsigned)__builtin_amdgcn_readfirstlane(ni.z));
        int c0 = (lane < deg) ? __builtin_nontemporal_load(&col[beg + lane]) : N;
        float t[8];
        gather64_pre(g4, col, beg, deg, c0, n, N, lane, t);
        float o[8];
#pragma unroll
        for (int j = 0; j < 8; ++j) {
            o[j] = fmaf(dn, t[j], bb[j]);
            if (RELU) o[j] = fmaxf(o[j], 0.f);
        }
        // 64 FMA against register W
        float p[8] = {};
#pragma unroll
        for (int j = 0; j < 8; ++j) {
            float oj = o[j];
#pragma unroll
            for (int i2 = 0; i2 < 4; ++i2) {
                unsigned wv = Wp[j * 4 + i2];
                p[2 * i2]     = fmaf(oj, __uint_as_float(wv << 16), p[2 * i2]);
                p[2 * i2 + 1] = fmaf(oj, __uint_as_float(wv & 0xffff0000u), p[2 * i2 + 1]);
            }
        }
        // butterfly transpose-reduce over s: res(lane 8q+s) = sum_s' p_s'[8q+s]
        bool b0 = (s & 1) != 0;
        float q1[4];
#pragma unroll
        for (int m = 0; m < 4; ++m) {
            float A = __shfl_xor(p[2 * m], 1, 64);
            float B = __shfl_xor(p[2 * m + 1], 1, 64);
            q1[m] = b0 ? (p[2 * m + 1] + B) : (p[2 * m] + A);
        }
        bool b1 = ((s >> 1) & 1) != 0;
        float q2[2];
#pragma unroll
        for (int m = 0; m < 2; ++m) {
            float A = __shfl_xor(q1[2 * m], 2, 64);
            float B = __shfl_xor(q1[2 * m + 1], 2, 64);
            q2[m] = b1 ? (q1[2 * m + 1] + B) : (q1[2 * m] + A);
        }
        bool b2 = ((s >> 2) & 1) != 0;
        float A = __shfl_xor(q2[0], 4, 64);
        float B = __shfl_xor(q2[1], 4, 64);
        float res = b2 ? (q2[1] + B) : (q2[0] + A);
        __builtin_nontemporal_store(f2bf(res * dn), &g_out[(size_t)n * HID + lane]);
    }
}

// ================= final aggregate + bias + log_softmax (r13, unchanged) ===

__global__ __launch_bounds__(256) void agg_lsm_kernel(
    const unsigned short* __restrict__ g_in, const int4* __restrict__ nodeinfo,
    const int* __restrict__ col, const float* __restrict__ bias,
    float* __restrict__ out, int N) {
    int tid = threadIdx.x, w = tid >> 6, lane = tid & 63;
    int eighth = lane >> 3, fo = lane & 7;
    const uint4* g4 = (const uint4*)g_in;
    float bb[8];
#pragma unroll
    for (int j = 0; j < 8; ++j) bb[j] = bias[8 * fo + j];
    const int ngrp = (N + 3) / 4;
    for (int grp = blockIdx.x; grp < ngrp; grp += gridDim.x) {
        int n = grp * 4 + w;
        if (n >= N) continue;
        int4 ni = nodeinfo[n];
        int beg = __builtin_amdgcn_readfirstlane(ni.x);
        int deg = __builtin_amdgcn_readfirstlane(ni.y);
        float dn = __uint_as_float((unsigned)__builtin_amdgcn_readfirstlane(ni.z));
        int c0 = (lane < deg) ? __builtin_nontemporal_load(&col[beg + lane]) : N;
        float t[8];
        gather64_pre(g4, col, beg, deg, c0, n, N, lane, t);
        float v[8];
#pragma unroll
        for (int k = 0; k < 8; ++k) v[k] = fmaf(dn, t[k], bb[k]);
        float mx = v[0];
#pragma unroll
        for (int k = 1; k < 8; ++k) mx = fmaxf(mx, v[k]);
        mx = fmaxf(mx, __shfl_xor(mx, 1, 64));
        mx = fmaxf(mx, __shfl_xor(mx, 2, 64));
        mx = fmaxf(mx, __shfl_xor(mx, 4, 64));
        float sum = 0.f;
#pragma unroll
        for (int k = 0; k < 8; ++k) sum += expf(v[k] - mx);
        sum += __shfl_xor(sum, 1, 64);
        sum += __shfl_xor(sum, 2, 64);
        sum += __shfl_xor(sum, 4, 64);
        float ls = mx + logf(sum);
        if (eighth == 0) {
            f32x4 o0 = {v[0] - ls, v[1] - ls, v[2] - ls, v[3] - ls};
            f32x4 o1 = {v[4] - ls, v[5] - ls, v[6] - ls, v[7] - ls};
            f32x4* op = (f32x4*)out;
            __builtin_nontemporal_store(o0, &op[(size_t)n * 16 + 2 * fo]);
            __builtin_nontemporal_store(o1, &op[(size_t)n * 16 + 2 * fo + 1]);
        }
    }
}

// ================= launcher =================

static inline size_t alignup(size_t x) { return (x + 255) & ~(size_t)255; }

extern "C" void kernel_launch(void* const* d_in, const int* in_sizes, int n_in,
                              void* d_out, int out_size, void* d_ws, size_t ws_size,
                              hipStream_t stream) {
    const float* x  = (const float*)d_in[0];
    const int*   ei = (const int*)d_in[1];
    const float* W1 = (const float*)d_in[2];
    const float* b1 = (const float*)d_in[3];
    const float* W2 = (const float*)d_in[4];
    const float* b2 = (const float*)d_in[5];

    const int N = in_sizes[0] / HID;  // 100000
    const int E = in_sizes[1] / 2;    // 1600000
    const int* src = ei;
    const int* dst = ei + E;

    const int nblk = (N + 255) / 256;  // 391 (<=512 required by scan)
    const int psz  = (N + 7) / 8;      // dst-range partition size

    char* w = (char*)d_ws;
    unsigned short* gA       = (unsigned short*)w; w += alignup((size_t)(N + 1) * HID * 2);
    unsigned short* gB       = (unsigned short*)w; w += alignup((size_t)(N + 1) * HID * 2);
    int4*           nodeinfo = (int4*)w;           w += alignup((size_t)N * 16);
    int*            cnt      = (int*)w;            w += alignup((size_t)N * 4);
    int*            cursor   = (int*)w;            w += alignup((size_t)N * 4);
    int*            col      = (int*)w;            w += alignup((size_t)E * 4);
    int*            bsums    = (int*)w;            w += alignup((size_t)nblk * 4);

    const int egrid  = (E + 255) / 256;
    const int gsgrid = 2048;  // grid-stride kernels

    // sentinel rows (index N) of both g buffers: zero once per launch
    (void)hipMemsetAsync(gA + (size_t)N * HID, 0, HID * sizeof(unsigned short), stream);
    (void)hipMemsetAsync(gB + (size_t)N * HID, 0, HID * sizeof(unsigned short), stream);

    // ---- CSR build (once; reused by all 3 convs) ----
    (void)hipMemsetAsync(cnt, 0, (size_t)N * sizeof(int), stream);
    hist_part_kernel<<<egrid * 8, 256, 0, stream>>>(dst, cnt, E, psz);
    bsum_kernel<<<nblk, 256, 0, stream>>>(cnt, bsums, N);
    scan_bsums_kernel<<<1, 512, 0, stream>>>(bsums, nblk);
    rowptr_kernel<<<nblk, 256, 0, stream>>>(cnt, bsums, nodeinfo, cursor, N);
    fill_part_kernel<<<egrid * 8, 256, 0, stream>>>(src, dst, cursor, col, E, psz);

    // ---- conv1 GEMM: gA = (x@W1)*dinv ----
    gemm_scale_kernel<<<gsgrid, 256, 0, stream>>>(x, W1, nodeinfo, gA, N);
    // ---- conv1 agg + b1 | conv2 GEMM: gB = ((agg(gA)+b1)@W1)*dinv ----
    agg_gemm_kernel<false><<<gsgrid, 256, 0, stream>>>(gA, nodeinfo, col, b1, W1, gB, N);
    // ---- conv2 agg + b1 + relu | conv3 GEMM: gA = (relu(agg(gB)+b1)@W2)*dinv ----
    agg_gemm_kernel<true><<<gsgrid, 256, 0, stream>>>(gB, nodeinfo, col, b1, W2, gA, N);
    // ---- conv3 agg + b2 + log_softmax -> d_out ----
    agg_lsm_kernel<<<gsgrid, 256, 0, stream>>>(gA, nodeinfo, col, b2, (float*)d_out, N);
}

// Round 15
// 404.654 us; speedup vs baseline: 1.2309x; 1.0266x over previous
//
#include <hip/hip_runtime.h>
#include <hip/hip_bf16.h>

#define HID 64

typedef float f32x4 __attribute__((ext_vector_type(4)));

// ---- bf16 helpers ----
__device__ __forceinline__ unsigned short f2bf(float f) {  // RNE f32->bf16
    unsigned u = __float_as_uint(f);
    return (unsigned short)((u + 0x7fffu + ((u >> 16) & 1u)) >> 16);
}
// a[0..7] += bf16x8 packed in uint4 (low ushort = even feat)
__device__ __forceinline__ void acc8(float* a, uint4 v) {
    a[0] += __uint_as_float(v.x << 16);
    a[1] += __uint_as_float(v.x & 0xffff0000u);
    a[2] += __uint_as_float(v.y << 16);
    a[3] += __uint_as_float(v.y & 0xffff0000u);
    a[4] += __uint_as_float(v.z << 16);
    a[5] += __uint_as_float(v.z & 0xffff0000u);
    a[6] += __uint_as_float(v.w << 16);
    a[7] += __uint_as_float(v.w & 0xffff0000u);
}

// ================= CSR build (by dst) =================

__global__ __launch_bounds__(256) void hist_part_kernel(
    const int* __restrict__ dst, int* __restrict__ cnt, int E, int psz) {
    int part = blockIdx.x & 7, chunk = blockIdx.x >> 3;
    int i = chunk * 256 + threadIdx.x;
    if (i >= E) return;
    int d = __builtin_nontemporal_load(&dst[i]);
    if (d / psz == part) atomicAdd(&cnt[d], 1);
}

__global__ __launch_bounds__(256) void bsum_kernel(const int* __restrict__ cnt,
                                                   int* __restrict__ bsums, int N) {
    __shared__ int s[256];
    int tid = threadIdx.x, i = blockIdx.x * 256 + tid;
    s[tid] = (i < N) ? cnt[i] : 0;
    __syncthreads();
    for (int o = 128; o > 0; o >>= 1) {
        if (tid < o) s[tid] += s[tid + o];
        __syncthreads();
    }
    if (tid == 0) bsums[blockIdx.x] = s[0];
}

__global__ __launch_bounds__(512) void scan_bsums_kernel(int* __restrict__ bsums, int nblk) {
    __shared__ int s[512];
    int tid = threadIdx.x;
    int orig = (tid < nblk) ? bsums[tid] : 0;
    s[tid] = orig;
    __syncthreads();
    for (int off = 1; off < 512; off <<= 1) {
        int v = (tid >= off) ? s[tid - off] : 0;
        __syncthreads();
        s[tid] += v;
        __syncthreads();
    }
    if (tid < nblk) bsums[tid] = s[tid] - orig;
}

// nodeinfo[n] = {row_ptr, deg, bits(dinv), 0}
__global__ __launch_bounds__(256) void rowptr_kernel(
    const int* __restrict__ cnt, const int* __restrict__ bsums,
    int4* __restrict__ nodeinfo, int* __restrict__ cursor, int N) {
    __shared__ int s[256];
    int tid = threadIdx.x, i = blockIdx.x * 256 + tid;
    int c = (i < N) ? cnt[i] : 0;
    s[tid] = c;
    __syncthreads();
    for (int off = 1; off < 256; off <<= 1) {
        int v = (tid >= off) ? s[tid - off] : 0;
        __syncthreads();
        s[tid] += v;
        __syncthreads();
    }
    if (i < N) {
        int excl = s[tid] - c + bsums[blockIdx.x];
        cursor[i] = excl;
        int4 ni;
        ni.x = excl;
        ni.y = c;
        ni.z = (int)__float_as_uint(rsqrtf((float)c + 1.0f));  // +1 self-loop
        ni.w = 0;
        nodeinfo[i] = ni;
    }
}

__global__ __launch_bounds__(256) void fill_part_kernel(
    const int* __restrict__ src, const int* __restrict__ dst,
    int* __restrict__ cursor, int* __restrict__ col, int E, int psz) {
    int part = blockIdx.x & 7, chunk = blockIdx.x >> 3;
    int i = chunk * 256 + threadIdx.x;
    if (i >= E) return;
    int d = __builtin_nontemporal_load(&dst[i]);
    if (d / psz == part) {
        int s = __builtin_nontemporal_load(&src[i]);
        int p = atomicAdd(&cursor[d], 1);
        col[p] = s;
    }
}

// ================= dual gather core =================
// TWO nodes per wave, interleaved: 2 independent load chains per lane -> 4+
// loads in flight (vs 2 single-node), one node's VALU hides the other's
// latency. Sentinel trick covers group-count mismatch (c lanes >= rem hold N,
// whose row is zeros and L1-hot).
__device__ __forceinline__ void gather64_dual(
    const uint4* __restrict__ g4, const int* __restrict__ col,
    int beg0, int deg0, int c0, int n0,
    int beg1, int deg1, int c1, int n1,
    int N, int lane, float* t0, float* t1) {
    int eighth = lane >> 3, fo = lane & 7;
    float A0[8] = {}, A1[8] = {};
    int dmax = deg0 > deg1 ? deg0 : deg1;
    int base = 0;
    while (true) {
        int rm = dmax - base; if (rm > 64) rm = 64;
        int gm = (rm + 7) >> 3;
        for (int j = 0; j < gm; ++j) {
            int s0 = __shfl(c0, 8 * j + eighth, 64);
            int s1 = __shfl(c1, 8 * j + eighth, 64);
            uint4 v0 = g4[(size_t)s0 * 8 + fo];
            uint4 v1 = g4[(size_t)s1 * 8 + fo];
            acc8(A0, v0);
            acc8(A1, v1);
        }
        base += 64;
        if (base >= dmax) break;
        c0 = (lane < deg0 - base) ? __builtin_nontemporal_load(&col[beg0 + base + lane]) : N;
        c1 = (lane < deg1 - base) ? __builtin_nontemporal_load(&col[beg1 + base + lane]) : N;
    }
    // self-loop rows
    uint4 sv0 = g4[(size_t)n0 * 8 + fo];
    uint4 sv1 = g4[(size_t)n1 * 8 + fo];
    float sf0[8] = {}, sf1[8] = {};
    acc8(sf0, sv0);
    acc8(sf1, sv1);
#pragma unroll
    for (int k = 0; k < 8; ++k) {
        float s0 = A0[k], s1 = A1[k];
        s0 += __shfl_xor(s0, 8, 64);
        s1 += __shfl_xor(s1, 8, 64);
        s0 += __shfl_xor(s0, 16, 64);
        s1 += __shfl_xor(s1, 16, 64);
        s0 += __shfl_xor(s0, 32, 64);
        s1 += __shfl_xor(s1, 32, 64);
        t0[k] = s0 + sf0[k];
        t1[k] = s1 + sf1[k];
    }
}

// ================= conv1 GEMM: g = bf16((X@W)*dinv) (r13, unchanged) =======

__global__ __launch_bounds__(256) void gemm_scale_kernel(
    const float* __restrict__ X, const float* __restrict__ W,
    const int4* __restrict__ nodeinfo, unsigned short* __restrict__ g, int N) {
    __shared__ float Ws[HID * HID];
    __shared__ float xs[4][HID];
    int tid = threadIdx.x;
    for (int i = tid; i < HID * HID; i += 256) Ws[i] = W[i];
    __syncthreads();
    int w = tid >> 6, c = tid & 63;
    float* xsw = xs[w];
    int ngrp = (N + 3) / 4;
    for (int grp = blockIdx.x; grp < ngrp; grp += gridDim.x) {
        int row = grp * 4 + w;
        if (row >= N) continue;
        xsw[c] = __builtin_nontemporal_load(&X[(size_t)row * HID + c]);
        float dn = __uint_as_float((unsigned)__builtin_amdgcn_readfirstlane(nodeinfo[row].z));
        float acc = 0.f;
#pragma unroll
        for (int k = 0; k < HID; ++k) acc = fmaf(xsw[k], Ws[k * HID + c], acc);
        __builtin_nontemporal_store(f2bf(acc * dn), &g[(size_t)row * HID + c]);
    }
}

// ---- register 8x8-block GEMM pieces (r14-proven) ----
// lane l (s=l&7,q=l>>3) holds W[8s+j][8q+i] packed bf16; butterfly over s.
__device__ __forceinline__ float reggemm_butterfly(
    const unsigned* Wp, const float* o, int s) {
    float p[8] = {};
#pragma unroll
    for (int j = 0; j < 8; ++j) {
        float oj = o[j];
#pragma unroll
        for (int i2 = 0; i2 < 4; ++i2) {
            unsigned wv = Wp[j * 4 + i2];
            p[2 * i2]     = fmaf(oj, __uint_as_float(wv << 16), p[2 * i2]);
            p[2 * i2 + 1] = fmaf(oj, __uint_as_float(wv & 0xffff0000u), p[2 * i2 + 1]);
        }
    }
    bool b0 = (s & 1) != 0;
    float q1[4];
#pragma unroll
    for (int m = 0; m < 4; ++m) {
        float A = __shfl_xor(p[2 * m], 1, 64);
        float B = __shfl_xor(p[2 * m + 1], 1, 64);
        q1[m] = b0 ? (p[2 * m + 1] + B) : (p[2 * m] + A);
    }
    bool b1 = ((s >> 1) & 1) != 0;
    float q2[2];
#pragma unroll
    for (int m = 0; m < 2; ++m) {
        float A = __shfl_xor(q1[2 * m], 2, 64);
        float B = __shfl_xor(q1[2 * m + 1], 2, 64);
        q2[m] = b1 ? (q1[2 * m + 1] + B) : (q1[2 * m] + A);
    }
    bool b2 = ((s >> 2) & 1) != 0;
    float A = __shfl_xor(q2[0], 4, 64);
    float B = __shfl_xor(q2[1], 4, 64);
    return b2 ? (q2[1] + B) : (q2[0] + A);
}

// ================= fused aggregate + epilogue + next-conv GEMM (2 nodes/wave)

template <bool RELU>
__global__ __launch_bounds__(256, 4) void agg_gemm_kernel(
    const unsigned short* __restrict__ g_in, const int4* __restrict__ nodeinfo,
    const int* __restrict__ col, const float* __restrict__ bias,
    const float* __restrict__ W, unsigned short* __restrict__ g_out, int N) {
    int tid = threadIdx.x, w = tid >> 6, lane = tid & 63;
    int s = lane & 7;
    unsigned Wp[32];
#pragma unroll
    for (int j = 0; j < 8; ++j)
#pragma unroll
        for (int i2 = 0; i2 < 4; ++i2) {
            float w0 = W[(8 * s + j) * HID + 8 * (lane >> 3) + 2 * i2];
            float w1 = W[(8 * s + j) * HID + 8 * (lane >> 3) + 2 * i2 + 1];
            Wp[j * 4 + i2] = (unsigned)f2bf(w0) | ((unsigned)f2bf(w1) << 16);
        }
    float bb[8];
#pragma unroll
    for (int j = 0; j < 8; ++j) bb[j] = bias[8 * s + j];
    const uint4* g4 = (const uint4*)g_in;
    const int ngrp = (N + 7) / 8;  // 8 nodes per block-iteration (2 per wave)
    for (int grp = blockIdx.x; grp < ngrp; grp += gridDim.x) {
        int n0 = grp * 8 + w;
        int n1 = n0 + 4;
        if (n0 >= N) continue;
        bool has1 = n1 < N;
        int4 ni0 = nodeinfo[n0];
        int4 ni1 = has1 ? nodeinfo[n1] : ni0;
        int beg0 = __builtin_amdgcn_readfirstlane(ni0.x);
        int deg0 = __builtin_amdgcn_readfirstlane(ni0.y);
        float dn0 = __uint_as_float((unsigned)__builtin_amdgcn_readfirstlane(ni0.z));
        int beg1 = __builtin_amdgcn_readfirstlane(ni1.x);
        int deg1 = has1 ? __builtin_amdgcn_readfirstlane(ni1.y) : 0;
        float dn1 = __uint_as_float((unsigned)__builtin_amdgcn_readfirstlane(ni1.z));
        int c0 = (lane < deg0) ? __builtin_nontemporal_load(&col[beg0 + lane]) : N;
        int c1 = (lane < deg1) ? __builtin_nontemporal_load(&col[beg1 + lane]) : N;
        float t0[8], t1[8];
        gather64_dual(g4, col, beg0, deg0, c0, n0, beg1, deg1, c1, has1 ? n1 : N,
                      N, lane, t0, t1);
        float o[8];
#pragma unroll
        for (int j = 0; j < 8; ++j) {
            o[j] = fmaf(dn0, t0[j], bb[j]);
            if (RELU) o[j] = fmaxf(o[j], 0.f);
        }
        float r0 = reggemm_butterfly(Wp, o, s);
        __builtin_nontemporal_store(f2bf(r0 * dn0), &g_out[(size_t)n0 * HID + lane]);
        if (has1) {
#pragma unroll
            for (int j = 0; j < 8; ++j) {
                o[j] = fmaf(dn1, t1[j], bb[j]);
                if (RELU) o[j] = fmaxf(o[j], 0.f);
            }
            float r1 = reggemm_butterfly(Wp, o, s);
            __builtin_nontemporal_store(f2bf(r1 * dn1), &g_out[(size_t)n1 * HID + lane]);
        }
    }
}

// ================= final aggregate + bias + log_softmax (2 nodes/wave) =====

__device__ __forceinline__ void lsm_store(
    const float* t, float dn, const float* bb, int n, int lane, float* out) {
    int eighth = lane >> 3, fo = lane & 7;
    float v[8];
#pragma unroll
    for (int k = 0; k < 8; ++k) v[k] = fmaf(dn, t[k], bb[k]);
    float mx = v[0];
#pragma unroll
    for (int k = 1; k < 8; ++k) mx = fmaxf(mx, v[k]);
    mx = fmaxf(mx, __shfl_xor(mx, 1, 64));
    mx = fmaxf(mx, __shfl_xor(mx, 2, 64));
    mx = fmaxf(mx, __shfl_xor(mx, 4, 64));
    float sum = 0.f;
#pragma unroll
    for (int k = 0; k < 8; ++k) sum += expf(v[k] - mx);
    sum += __shfl_xor(sum, 1, 64);
    sum += __shfl_xor(sum, 2, 64);
    sum += __shfl_xor(sum, 4, 64);
    float ls = mx + logf(sum);
    if (eighth == 0) {
        f32x4 o0 = {v[0] - ls, v[1] - ls, v[2] - ls, v[3] - ls};
        f32x4 o1 = {v[4] - ls, v[5] - ls, v[6] - ls, v[7] - ls};
        f32x4* op = (f32x4*)out;
        __builtin_nontemporal_store(o0, &op[(size_t)n * 16 + 2 * fo]);
        __builtin_nontemporal_store(o1, &op[(size_t)n * 16 + 2 * fo + 1]);
    }
}

__global__ __launch_bounds__(256, 4) void agg_lsm_kernel(
    const unsigned short* __restrict__ g_in, const int4* __restrict__ nodeinfo,
    const int* __restrict__ col, const float* __restrict__ bias,
    float* __restrict__ out, int N) {
    int tid = threadIdx.x, w = tid >> 6, lane = tid & 63;
    int fo = lane & 7;
    const uint4* g4 = (const uint4*)g_in;
    float bb[8];
#pragma unroll
    for (int j = 0; j < 8; ++j) bb[j] = bias[8 * fo + j];
    const int ngrp = (N + 7) / 8;
    for (int grp = blockIdx.x; grp < ngrp; grp += gridDim.x) {
        int n0 = grp * 8 + w;
        int n1 = n0 + 4;
        if (n0 >= N) continue;
        bool has1 = n1 < N;
        int4 ni0 = nodeinfo[n0];
        int4 ni1 = has1 ? nodeinfo[n1] : ni0;
        int beg0 = __builtin_amdgcn_readfirstlane(ni0.x);
        int deg0 = __builtin_amdgcn_readfirstlane(ni0.y);
        float dn0 = __uint_as_float((unsigned)__builtin_amdgcn_readfirstlane(ni0.z));
        int beg1 = __builtin_amdgcn_readfirstlane(ni1.x);
        int deg1 = has1 ? __builtin_amdgcn_readfirstlane(ni1.y) : 0;
        float dn1 = __uint_as_float((unsigned)__builtin_amdgcn_readfirstlane(ni1.z));
        int c0 = (lane < deg0) ? __builtin_nontemporal_load(&col[beg0 + lane]) : N;
        int c1 = (lane < deg1) ? __builtin_nontemporal_load(&col[beg1 + lane]) : N;
        float t0[8], t1[8];
        gather64_dual(g4, col, beg0, deg0, c0, n0, beg1, deg1, c1, has1 ? n1 : N,
                      N, lane, t0, t1);
        lsm_store(t0, dn0, bb, n0, lane, out);
        if (has1) lsm_store(t1, dn1, bb, n1, lane, out);
    }
}

// ================= launcher =================

static inline size_t alignup(size_t x) { return (x + 255) & ~(size_t)255; }

extern "C" void kernel_launch(void* const* d_in, const int* in_sizes, int n_in,
                              void* d_out, int out_size, void* d_ws, size_t ws_size,
                              hipStream_t stream) {
    const float* x  = (const float*)d_in[0];
    const int*   ei = (const int*)d_in[1];
    const float* W1 = (const float*)d_in[2];
    const float* b1 = (const float*)d_in[3];
    const float* W2 = (const float*)d_in[4];
    const float* b2 = (const float*)d_in[5];

    const int N = in_sizes[0] / HID;  // 100000
    const int E = in_sizes[1] / 2;    // 1600000
    const int* src = ei;
    const int* dst = ei + E;

    const int nblk = (N + 255) / 256;  // 391 (<=512 required by scan)
    const int psz  = (N + 7) / 8;      // dst-range partition size

    char* w = (char*)d_ws;
    unsigned short* gA       = (unsigned short*)w; w += alignup((size_t)(N + 1) * HID * 2);
    unsigned short* gB       = (unsigned short*)w; w += alignup((size_t)(N + 1) * HID * 2);
    int4*           nodeinfo = (int4*)w;           w += alignup((size_t)N * 16);
    int*            cnt      = (int*)w;            w += alignup((size_t)N * 4);
    int*            cursor   = (int*)w;            w += alignup((size_t)N * 4);
    int*            col      = (int*)w;            w += alignup((size_t)E * 4);
    int*            bsums    = (int*)w;            w += alignup((size_t)nblk * 4);

    const int egrid  = (E + 255) / 256;
    const int gsgrid = 2048;  // grid-stride kernels

    // sentinel rows (index N) of both g buffers: zero once per launch
    (void)hipMemsetAsync(gA + (size_t)N * HID, 0, HID * sizeof(unsigned short), stream);
    (void)hipMemsetAsync(gB + (size_t)N * HID, 0, HID * sizeof(unsigned short), stream);

    // ---- CSR build (once; reused by all 3 convs) ----
    (void)hipMemsetAsync(cnt, 0, (size_t)N * sizeof(int), stream);
    hist_part_kernel<<<egrid * 8, 256, 0, stream>>>(dst, cnt, E, psz);
    bsum_kernel<<<nblk, 256, 0, stream>>>(cnt, bsums, N);
    scan_bsums_kernel<<<1, 512, 0, stream>>>(bsums, nblk);
    rowptr_kernel<<<nblk, 256, 0, stream>>>(cnt, bsums, nodeinfo, cursor, N);
    fill_part_kernel<<<egrid * 8, 256, 0, stream>>>(src, dst, cursor, col, E, psz);

    // ---- conv1 GEMM: gA = (x@W1)*dinv ----
    gemm_scale_kernel<<<gsgrid, 256, 0, stream>>>(x, W1, nodeinfo, gA, N);
    // ---- conv1 agg + b1 | conv2 GEMM: gB = ((agg(gA)+b1)@W1)*dinv ----
    agg_gemm_kernel<false><<<gsgrid, 256, 0, stream>>>(gA, nodeinfo, col, b1, W1, gB, N);
    // ---- conv2 agg + b1 + relu | conv3 GEMM: gA = (relu(agg(gB)+b1)@W2)*dinv ----
    agg_gemm_kernel<true><<<gsgrid, 256, 0, stream>>>(gB, nodeinfo, col, b1, W2, gA, N);
    // ---- conv3 agg + b2 + log_softmax -> d_out ----
    agg_lsm_kernel<<<gsgrid, 256, 0, stream>>>(gA, nodeinfo, col, b2, (float*)d_out, N);
}